// Round 2
// baseline (1420.588 us; speedup 1.0000x reference)
//
#include <hip/hip_runtime.h>

#define T_STEPS 512
#define HS 20        // hidden size
#define F0 10        // input features (layer 0)
#define NBATCH 3     // batches per wave (lanes 0..59 active)
#define NB_TOT 4096

__device__ __forceinline__ float sigmoid_fast(float v) {
    return __fdividef(1.f, 1.f + __expf(-v));
}
__device__ __forceinline__ float tanh_fast(float v) {
    return 1.f - __fdividef(2.f, __expf(2.f * v) + 1.f);
}

// One wave per block. Lane layout: b = tid/20 (batch within block), u = tid%20
// (hidden unit). Lane (b,u) owns rows {u, 20+u, 40+u, 60+u} of both layers'
// gate matrices -> i/f/g/o and the c-update are lane-local. h broadcast via
// tiny LDS arrays; single-wave => DS ops are program-ordered, NO barriers.
__global__ __launch_bounds__(64, 1)
void lstm2_fc_kernel(const float* __restrict__ x,
                     const float* __restrict__ wih0, const float* __restrict__ whh0,
                     const float* __restrict__ bih0, const float* __restrict__ bhh0,
                     const float* __restrict__ wih1, const float* __restrict__ whh1,
                     const float* __restrict__ bih1, const float* __restrict__ bhh1,
                     const float* __restrict__ wfc,  const float* __restrict__ bfc,
                     float* __restrict__ out)
{
    const int tid = threadIdx.x;
    const int b   = tid / HS;          // 0..3 (3 == spill lanes 60..63)
    const int u   = tid % HS;
    const int bg  = blockIdx.x * NBATCH + b;
    const bool valid = (b < NBATCH) && (bg < NB_TOT);
    const int bgc = (bg < NB_TOT) ? bg : (NB_TOT - 1);

    __shared__ float s_h0[4][HS];      // row 3 absorbs lanes 60..63
    __shared__ float s_h1[4][HS];

    for (int i = tid; i < 4 * HS; i += 64) {
        (&s_h0[0][0])[i] = 0.f;
        (&s_h1[0][0])[i] = 0.f;
    }

    // ---- per-lane register weights: 4 gate rows (i,f,g,o) per layer ----
    float wi0[4][F0], wh0[4][HS], wi1[4][HS], wh1[4][HS], bb0[4], bb1[4];
    #pragma unroll
    for (int g = 0; g < 4; ++g) {
        const int row = g * HS + u;
        #pragma unroll
        for (int f = 0; f < F0; ++f) wi0[g][f] = wih0[row * F0 + f];
        #pragma unroll
        for (int j = 0; j < HS; ++j) wh0[g][j] = whh0[row * HS + j];
        #pragma unroll
        for (int j = 0; j < HS; ++j) wi1[g][j] = wih1[row * HS + j];
        #pragma unroll
        for (int j = 0; j < HS; ++j) wh1[g][j] = whh1[row * HS + j];
        bb0[g] = bih0[row] + bhh0[row];
        bb1[g] = bih1[row] + bhh1[row];
    }

    float c0 = 0.f, c1 = 0.f;

    const float* xb = x + (size_t)bgc * T_STEPS * F0;
    float xc[F0], xn[F0];
    {
        const float2* p = (const float2*)xb;      // 8B-aligned (stride 40B)
        #pragma unroll
        for (int f = 0; f < F0 / 2; ++f) {
            float2 v = p[f];
            xc[2 * f] = v.x; xc[2 * f + 1] = v.y;
        }
    }

    __syncthreads();   // once, before the loop (init visibility; single wave anyway)

    for (int t = 0; t < T_STEPS; ++t) {
        // prefetch next x (broadcast within the 20-lane batch group)
        if (t + 1 < T_STEPS) {
            const float2* p = (const float2*)(xb + (t + 1) * F0);
            #pragma unroll
            for (int f = 0; f < F0 / 2; ++f) {
                float2 v = p[f];
                xn[2 * f] = v.x; xn[2 * f + 1] = v.y;
            }
        }

        // snapshot h0(t-1), h1(t-1)  (16B-aligned rows of 20 floats)
        float h0r[HS], h1r[HS];
        {
            const float4* p0 = (const float4*)(&s_h0[b][0]);
            const float4* p1 = (const float4*)(&s_h1[b][0]);
            #pragma unroll
            for (int q = 0; q < HS / 4; ++q) {
                float4 v0 = p0[q], v1 = p1[q];
                h0r[4*q] = v0.x; h0r[4*q+1] = v0.y; h0r[4*q+2] = v0.z; h0r[4*q+3] = v0.w;
                h1r[4*q] = v1.x; h1r[4*q+1] = v1.y; h1r[4*q+2] = v1.z; h1r[4*q+3] = v1.w;
            }
        }

        // ================= layer 0 (lane-local gates) =================
        float a0 = bb0[0], a1 = bb0[1], a2 = bb0[2], a3 = bb0[3];
        #pragma unroll
        for (int f = 0; f < F0; ++f) {
            const float xf = xc[f];
            a0 = fmaf(xf, wi0[0][f], a0);
            a1 = fmaf(xf, wi0[1][f], a1);
            a2 = fmaf(xf, wi0[2][f], a2);
            a3 = fmaf(xf, wi0[3][f], a3);
        }
        #pragma unroll
        for (int j = 0; j < HS; ++j) {
            const float hj = h0r[j];
            a0 = fmaf(hj, wh0[0][j], a0);
            a1 = fmaf(hj, wh0[1][j], a1);
            a2 = fmaf(hj, wh0[2][j], a2);
            a3 = fmaf(hj, wh0[3][j], a3);
        }
        {
            const float ii = sigmoid_fast(a0), ff = sigmoid_fast(a1);
            const float gg = tanh_fast(a2),    oo = sigmoid_fast(a3);
            c0 = ff * c0 + ii * gg;
            s_h0[b][u] = oo * tanh_fast(c0);
        }
        __builtin_amdgcn_wave_barrier();   // order write before broadcast re-read

        // broadcast h0(t)
        float h0n[HS];
        {
            const float4* p0 = (const float4*)(&s_h0[b][0]);
            #pragma unroll
            for (int q = 0; q < HS / 4; ++q) {
                float4 v0 = p0[q];
                h0n[4*q] = v0.x; h0n[4*q+1] = v0.y; h0n[4*q+2] = v0.z; h0n[4*q+3] = v0.w;
            }
        }

        // ================= layer 1 (lane-local gates) =================
        float d0 = bb1[0], d1 = bb1[1], d2 = bb1[2], d3 = bb1[3];
        #pragma unroll
        for (int j = 0; j < HS; ++j) {
            const float hj = h0n[j];
            d0 = fmaf(hj, wi1[0][j], d0);
            d1 = fmaf(hj, wi1[1][j], d1);
            d2 = fmaf(hj, wi1[2][j], d2);
            d3 = fmaf(hj, wi1[3][j], d3);
        }
        #pragma unroll
        for (int j = 0; j < HS; ++j) {
            const float hj = h1r[j];
            d0 = fmaf(hj, wh1[0][j], d0);
            d1 = fmaf(hj, wh1[1][j], d1);
            d2 = fmaf(hj, wh1[2][j], d2);
            d3 = fmaf(hj, wh1[3][j], d3);
        }
        {
            const float ii = sigmoid_fast(d0), ff = sigmoid_fast(d1);
            const float gg = tanh_fast(d2),    oo = sigmoid_fast(d3);
            c1 = ff * c1 + ii * gg;
            s_h1[b][u] = oo * tanh_fast(c1);
        }
        __builtin_amdgcn_wave_barrier();

        #pragma unroll
        for (int f = 0; f < F0; ++f) xc[f] = xn[f];
    }

    // ================= final FC =================
    if (valid && u == 0) {
        float o = bfc[0];
        #pragma unroll
        for (int j = 0; j < HS; ++j) o = fmaf(s_h1[b][j], wfc[j], o);
        out[bg] = o;
    }
}

extern "C" void kernel_launch(void* const* d_in, const int* in_sizes, int n_in,
                              void* d_out, int out_size, void* d_ws, size_t ws_size,
                              hipStream_t stream) {
    const float* x    = (const float*)d_in[0];
    const float* wih0 = (const float*)d_in[1];
    const float* whh0 = (const float*)d_in[2];
    const float* bih0 = (const float*)d_in[3];
    const float* bhh0 = (const float*)d_in[4];
    const float* wih1 = (const float*)d_in[5];
    const float* whh1 = (const float*)d_in[6];
    const float* bih1 = (const float*)d_in[7];
    const float* bhh1 = (const float*)d_in[8];
    const float* wfc  = (const float*)d_in[9];
    const float* bfc  = (const float*)d_in[10];
    float* out = (float*)d_out;

    dim3 grid((NB_TOT + NBATCH - 1) / NBATCH), block(64);
    hipLaunchKernelGGL(lstm2_fc_kernel, grid, block, 0, stream,
                       x, wih0, whh0, bih0, bhh0,
                       wih1, whh1, bih1, bhh1, wfc, bfc, out);
}

// Round 3
// 1416.291 us; speedup vs baseline: 1.0030x; 1.0030x over previous
//
#include <hip/hip_runtime.h>

#define T_STEPS 512
#define HS 20        // hidden size
#define F0 10        // input features (layer 0)
#define BPB 6        // batches per block: lane-group b handles batches {b, b+3}
#define NB_TOT 4096
#define NBLK ((NB_TOT + BPB - 1) / BPB)   // 683

__device__ __forceinline__ float sigmoid_fast(float v) {
    return __fdividef(1.f, 1.f + __expf(-v));
}
__device__ __forceinline__ float tanh_fast(float v) {
    return 1.f - __fdividef(2.f, __expf(2.f * v) + 1.f);
}

// Defeat load rematerialization: value becomes asm-defined, compiler must
// keep it in a VGPR instead of re-loading from global inside the t-loop.
#define PIN(v) asm volatile("" : "+v"(v))

__global__ __launch_bounds__(64, 1)
void lstm2_fc_kernel(const float* __restrict__ x,
                     const float* __restrict__ wih0, const float* __restrict__ whh0,
                     const float* __restrict__ bih0, const float* __restrict__ bhh0,
                     const float* __restrict__ wih1, const float* __restrict__ whh1,
                     const float* __restrict__ bih1, const float* __restrict__ bhh1,
                     const float* __restrict__ wfc,  const float* __restrict__ bfc,
                     float* __restrict__ out)
{
    const int tid = threadIdx.x;
    int b = tid / HS;                    // 0..3
    if (b == 3) b = 0;                   // lanes 60..63 shadow lanes 0..3 (benign dup)
    const int u  = tid % HS;
    const int bgA = blockIdx.x * BPB + b;        // always < 4096 (683*6+2 max = 4094)
    const int bgBr = blockIdx.x * BPB + b + 3;
    const bool okB = (bgBr < NB_TOT);
    const int bgB = okB ? bgBr : (NB_TOT - 1);   // clamp reads

    __shared__ float s_h0[BPB][HS];
    __shared__ float s_h1[BPB][HS];

    for (int i = tid; i < BPB * HS; i += 64) {
        (&s_h0[0][0])[i] = 0.f;
        (&s_h1[0][0])[i] = 0.f;
    }

    // ---- per-lane register weights (shared by both batch tasks), pinned ----
    float wi0[4][F0], wh0[4][HS], wi1[4][HS], wh1[4][HS], bb0[4], bb1[4];
    #pragma unroll
    for (int g = 0; g < 4; ++g) {
        const int row = g * HS + u;
        #pragma unroll
        for (int f = 0; f < F0; ++f) { wi0[g][f] = wih0[row * F0 + f]; PIN(wi0[g][f]); }
        #pragma unroll
        for (int j = 0; j < HS; ++j) { wh0[g][j] = whh0[row * HS + j]; PIN(wh0[g][j]); }
        #pragma unroll
        for (int j = 0; j < HS; ++j) { wi1[g][j] = wih1[row * HS + j]; PIN(wi1[g][j]); }
        #pragma unroll
        for (int j = 0; j < HS; ++j) { wh1[g][j] = whh1[row * HS + j]; PIN(wh1[g][j]); }
        bb0[g] = bih0[row] + bhh0[row];  PIN(bb0[g]);
        bb1[g] = bih1[row] + bhh1[row];  PIN(bb1[g]);
    }

    float cA0 = 0.f, cA1 = 0.f, cB0 = 0.f, cB1 = 0.f;

    const float* xbA = x + (size_t)bgA * T_STEPS * F0;
    const float* xbB = x + (size_t)bgB * T_STEPS * F0;
    float xcA[F0], xcB[F0], xnA[F0], xnB[F0];
    {
        const float2* pA = (const float2*)xbA;
        const float2* pB = (const float2*)xbB;
        #pragma unroll
        for (int f = 0; f < F0 / 2; ++f) {
            float2 vA = pA[f], vB = pB[f];
            xcA[2*f] = vA.x; xcA[2*f+1] = vA.y;
            xcB[2*f] = vB.x; xcB[2*f+1] = vB.y;
        }
    }

    __syncthreads();

    for (int t = 0; t < T_STEPS; ++t) {
        // prefetch next timestep's x for both tasks
        if (t + 1 < T_STEPS) {
            const float2* pA = (const float2*)(xbA + (t + 1) * F0);
            const float2* pB = (const float2*)(xbB + (t + 1) * F0);
            #pragma unroll
            for (int f = 0; f < F0 / 2; ++f) {
                float2 vA = pA[f], vB = pB[f];
                xnA[2*f] = vA.x; xnA[2*f+1] = vA.y;
                xnB[2*f] = vB.x; xnB[2*f+1] = vB.y;
            }
        }

        // ================= layer 0: gates for tasks A and B =================
        float aA0 = bb0[0], aA1 = bb0[1], aA2 = bb0[2], aA3 = bb0[3];
        float aB0 = bb0[0], aB1 = bb0[1], aB2 = bb0[2], aB3 = bb0[3];
        #pragma unroll
        for (int f = 0; f < F0; ++f) {
            const float xA = xcA[f], xB = xcB[f];
            aA0 = fmaf(xA, wi0[0][f], aA0);  aB0 = fmaf(xB, wi0[0][f], aB0);
            aA1 = fmaf(xA, wi0[1][f], aA1);  aB1 = fmaf(xB, wi0[1][f], aB1);
            aA2 = fmaf(xA, wi0[2][f], aA2);  aB2 = fmaf(xB, wi0[2][f], aB2);
            aA3 = fmaf(xA, wi0[3][f], aA3);  aB3 = fmaf(xB, wi0[3][f], aB3);
        }
        #pragma unroll
        for (int q = 0; q < HS / 4; ++q) {
            const float4 hA = *(const float4*)(&s_h0[b][4 * q]);
            const float4 hB = *(const float4*)(&s_h0[b + 3][4 * q]);
            const float eA[4] = {hA.x, hA.y, hA.z, hA.w};
            const float eB[4] = {hB.x, hB.y, hB.z, hB.w};
            #pragma unroll
            for (int e = 0; e < 4; ++e) {
                const int j = 4 * q + e;
                aA0 = fmaf(eA[e], wh0[0][j], aA0);  aB0 = fmaf(eB[e], wh0[0][j], aB0);
                aA1 = fmaf(eA[e], wh0[1][j], aA1);  aB1 = fmaf(eB[e], wh0[1][j], aB1);
                aA2 = fmaf(eA[e], wh0[2][j], aA2);  aB2 = fmaf(eB[e], wh0[2][j], aB2);
                aA3 = fmaf(eA[e], wh0[3][j], aA3);  aB3 = fmaf(eB[e], wh0[3][j], aB3);
            }
        }
        {
            const float iA = sigmoid_fast(aA0), fA = sigmoid_fast(aA1);
            const float gA = tanh_fast(aA2),    oA = sigmoid_fast(aA3);
            cA0 = fA * cA0 + iA * gA;
            s_h0[b][u] = oA * tanh_fast(cA0);
            const float iB = sigmoid_fast(aB0), fB = sigmoid_fast(aB1);
            const float gB = tanh_fast(aB2),    oB = sigmoid_fast(aB3);
            cB0 = fB * cB0 + iB * gB;
            s_h0[b + 3][u] = oB * tanh_fast(cB0);
        }
        __builtin_amdgcn_wave_barrier();

        // ================= layer 1: gates for tasks A and B =================
        float dA0 = bb1[0], dA1 = bb1[1], dA2 = bb1[2], dA3 = bb1[3];
        float dB0 = bb1[0], dB1 = bb1[1], dB2 = bb1[2], dB3 = bb1[3];
        #pragma unroll
        for (int q = 0; q < HS / 4; ++q) {
            const float4 hA = *(const float4*)(&s_h0[b][4 * q]);       // h0(t)
            const float4 hB = *(const float4*)(&s_h0[b + 3][4 * q]);
            const float4 pA = *(const float4*)(&s_h1[b][4 * q]);       // h1(t-1)
            const float4 pB = *(const float4*)(&s_h1[b + 3][4 * q]);
            const float eA[4] = {hA.x, hA.y, hA.z, hA.w};
            const float eB[4] = {hB.x, hB.y, hB.z, hB.w};
            const float fA[4] = {pA.x, pA.y, pA.z, pA.w};
            const float fB[4] = {pB.x, pB.y, pB.z, pB.w};
            #pragma unroll
            for (int e = 0; e < 4; ++e) {
                const int j = 4 * q + e;
                dA0 = fmaf(eA[e], wi1[0][j], dA0);  dB0 = fmaf(eB[e], wi1[0][j], dB0);
                dA1 = fmaf(eA[e], wi1[1][j], dA1);  dB1 = fmaf(eB[e], wi1[1][j], dB1);
                dA2 = fmaf(eA[e], wi1[2][j], dA2);  dB2 = fmaf(eB[e], wi1[2][j], dB2);
                dA3 = fmaf(eA[e], wi1[3][j], dA3);  dB3 = fmaf(eB[e], wi1[3][j], dB3);
                dA0 = fmaf(fA[e], wh1[0][j], dA0);  dB0 = fmaf(fB[e], wh1[0][j], dB0);
                dA1 = fmaf(fA[e], wh1[1][j], dA1);  dB1 = fmaf(fB[e], wh1[1][j], dB1);
                dA2 = fmaf(fA[e], wh1[2][j], dA2);  dB2 = fmaf(fB[e], wh1[2][j], dB2);
                dA3 = fmaf(fA[e], wh1[3][j], dA3);  dB3 = fmaf(fB[e], wh1[3][j], dB3);
            }
        }
        __builtin_amdgcn_wave_barrier();   // h1(t-1) reads done before overwrite
        {
            const float iA = sigmoid_fast(dA0), fA = sigmoid_fast(dA1);
            const float gA = tanh_fast(dA2),    oA = sigmoid_fast(dA3);
            cA1 = fA * cA1 + iA * gA;
            s_h1[b][u] = oA * tanh_fast(cA1);
            const float iB = sigmoid_fast(dB0), fB = sigmoid_fast(dB1);
            const float gB = tanh_fast(dB2),    oB = sigmoid_fast(dB3);
            cB1 = fB * cB1 + iB * gB;
            s_h1[b + 3][u] = oB * tanh_fast(cB1);
        }
        __builtin_amdgcn_wave_barrier();

        #pragma unroll
        for (int f = 0; f < F0; ++f) { xcA[f] = xnA[f]; xcB[f] = xnB[f]; }
    }

    // ================= final FC =================
    if (tid < 60 && u == 0) {
        float oA = bfc[0], oB = bfc[0];
        #pragma unroll
        for (int j = 0; j < HS; ++j) {
            oA = fmaf(s_h1[b][j],     wfc[j], oA);
            oB = fmaf(s_h1[b + 3][j], wfc[j], oB);
        }
        out[bgA] = oA;
        if (okB) out[bgBr] = oB;
    }
}

extern "C" void kernel_launch(void* const* d_in, const int* in_sizes, int n_in,
                              void* d_out, int out_size, void* d_ws, size_t ws_size,
                              hipStream_t stream) {
    const float* x    = (const float*)d_in[0];
    const float* wih0 = (const float*)d_in[1];
    const float* whh0 = (const float*)d_in[2];
    const float* bih0 = (const float*)d_in[3];
    const float* bhh0 = (const float*)d_in[4];
    const float* wih1 = (const float*)d_in[5];
    const float* whh1 = (const float*)d_in[6];
    const float* bih1 = (const float*)d_in[7];
    const float* bhh1 = (const float*)d_in[8];
    const float* wfc  = (const float*)d_in[9];
    const float* bfc  = (const float*)d_in[10];
    float* out = (float*)d_out;

    dim3 grid(NBLK), block(64);
    hipLaunchKernelGGL(lstm2_fc_kernel, grid, block, 0, stream,
                       x, wih0, whh0, bih0, bhh0,
                       wih1, whh1, bih1, bhh1, wfc, bfc, out);
}

// Round 4
// 993.975 us; speedup vs baseline: 1.4292x; 1.4249x over previous
//
#include <hip/hip_runtime.h>

#define T_STEPS 512
#define HS 20       // hidden size
#define F0 10       // input features (layer 0)
#define BPB 3       // batches per block (20-lane groups)
#define NB_TOT 4096
#define NBLK ((NB_TOT + BPB - 1) / BPB)   // 1366

__device__ __forceinline__ float sigmoid_fast(float v) {
    return __fdividef(1.f, 1.f + __expf(-v));
}
__device__ __forceinline__ float tanh_fast(float v) {
    return 1.f - __fdividef(2.f, __expf(2.f * v) + 1.f);
}
#define PIN(v) asm volatile("" : "+v"(v))

// Block = 2 waves. Wave0: layer0 for 3 batches (lane = (batch,unit), 4 gate
// rows of W0 in VGPRs = 124 floats). Wave1: layer1 (164 floats). Wave1 runs
// one timestep behind wave0 (software pipeline, semantics exact). h0 crosses
// waves via double-buffered LDS; ONE __syncthreads per iteration.
__global__ __launch_bounds__(128, 2)
void lstm2_fc_kernel(const float* __restrict__ x,
                     const float* __restrict__ wih0, const float* __restrict__ whh0,
                     const float* __restrict__ bih0, const float* __restrict__ bhh0,
                     const float* __restrict__ wih1, const float* __restrict__ whh1,
                     const float* __restrict__ bih1, const float* __restrict__ bhh1,
                     const float* __restrict__ wfc,  const float* __restrict__ bfc,
                     float* __restrict__ out)
{
    const int tid  = threadIdx.x;
    const int wid  = tid >> 6;
    const int lane = tid & 63;
    const int g    = (lane / HS) % BPB;   // lanes 60..63 shadow group 0 (benign dups)
    const int u    = lane % HS;
    const int bg   = blockIdx.x * BPB + g;
    const int bgc  = (bg < NB_TOT) ? bg : (NB_TOT - 1);

    __shared__ float s_h0[2][BPB][HS];   // double buffer: wave0 -> wave1 (and wave0 self)
    __shared__ float s_h1[BPB][HS];      // wave1-private recurrence state

    for (int i = tid; i < 2 * BPB * HS; i += 128) (&s_h0[0][0][0])[i] = 0.f;
    for (int i = tid; i < BPB * HS; i += 128)     (&s_h1[0][0])[i]    = 0.f;

    // ---- per-lane weights, shared storage between the two wave roles ----
    float w[4][2 * HS], bias[4];
    if (wid == 0) {
        #pragma unroll
        for (int q = 0; q < 4; ++q) {
            const int row = q * HS + u;
            #pragma unroll
            for (int f = 0; f < F0; ++f) { w[q][f] = wih0[row * F0 + f]; PIN(w[q][f]); }
            #pragma unroll
            for (int j = 0; j < HS; ++j) { w[q][F0 + j] = whh0[row * HS + j]; PIN(w[q][F0 + j]); }
            bias[q] = bih0[row] + bhh0[row]; PIN(bias[q]);
        }
    } else {
        #pragma unroll
        for (int q = 0; q < 4; ++q) {
            const int row = q * HS + u;
            #pragma unroll
            for (int j = 0; j < HS; ++j) { w[q][j]      = wih1[row * HS + j]; PIN(w[q][j]); }
            #pragma unroll
            for (int j = 0; j < HS; ++j) { w[q][HS + j] = whh1[row * HS + j]; PIN(w[q][HS + j]); }
            bias[q] = bih1[row] + bhh1[row]; PIN(bias[q]);
        }
    }

    float cst = 0.f;                     // c0 (wave0) or c1 (wave1) for (bg, u)
    const float* xb = x + (size_t)bgc * (T_STEPS * F0);
    float xc[F0];
    if (wid == 0) {
        #pragma unroll
        for (int f = 0; f < F0 / 2; ++f) {
            float2 v = ((const float2*)xb)[f];
            xc[2 * f] = v.x; xc[2 * f + 1] = v.y;
        }
    }

    __syncthreads();

    for (int t = 0; t <= T_STEPS; ++t) {
        if (wid == 0) {
            if (t < T_STEPS) {
                // prefetch x(t+1)
                float xn[F0];
                if (t + 1 < T_STEPS) {
                    #pragma unroll
                    for (int f = 0; f < F0 / 2; ++f) {
                        float2 v = ((const float2*)(xb + (t + 1) * F0))[f];
                        xn[2 * f] = v.x; xn[2 * f + 1] = v.y;
                    }
                } else {
                    #pragma unroll
                    for (int f = 0; f < F0; ++f) xn[f] = 0.f;
                }

                float a0 = bias[0], a1 = bias[1], a2 = bias[2], a3 = bias[3];
                #pragma unroll
                for (int f = 0; f < F0; ++f) {
                    const float xf = xc[f];
                    a0 = fmaf(xf, w[0][f], a0);
                    a1 = fmaf(xf, w[1][f], a1);
                    a2 = fmaf(xf, w[2][f], a2);
                    a3 = fmaf(xf, w[3][f], a3);
                }
                const float* hp = &s_h0[(t & 1) ^ 1][g][0];   // h0(t-1)
                #pragma unroll
                for (int q = 0; q < HS / 4; ++q) {
                    const float4 h4 = *(const float4*)(hp + 4 * q);
                    const float e[4] = {h4.x, h4.y, h4.z, h4.w};
                    #pragma unroll
                    for (int s = 0; s < 4; ++s) {
                        const int k = F0 + 4 * q + s;
                        a0 = fmaf(e[s], w[0][k], a0);
                        a1 = fmaf(e[s], w[1][k], a1);
                        a2 = fmaf(e[s], w[2][k], a2);
                        a3 = fmaf(e[s], w[3][k], a3);
                    }
                }
                const float ii = sigmoid_fast(a0), ff = sigmoid_fast(a1);
                const float gg = tanh_fast(a2),    oo = sigmoid_fast(a3);
                cst = ff * cst + ii * gg;
                s_h0[t & 1][g][u] = oo * tanh_fast(cst);
                #pragma unroll
                for (int f = 0; f < F0; ++f) xc[f] = xn[f];
            }
        } else {
            if (t >= 1) {
                // layer1 computes step s = t-1
                float a0 = bias[0], a1 = bias[1], a2 = bias[2], a3 = bias[3];
                const float* hp0 = &s_h0[(t - 1) & 1][g][0];  // h0(s)
                #pragma unroll
                for (int q = 0; q < HS / 4; ++q) {
                    const float4 h4 = *(const float4*)(hp0 + 4 * q);
                    const float e[4] = {h4.x, h4.y, h4.z, h4.w};
                    #pragma unroll
                    for (int s = 0; s < 4; ++s) {
                        const int k = 4 * q + s;
                        a0 = fmaf(e[s], w[0][k], a0);
                        a1 = fmaf(e[s], w[1][k], a1);
                        a2 = fmaf(e[s], w[2][k], a2);
                        a3 = fmaf(e[s], w[3][k], a3);
                    }
                }
                const float* hp1 = &s_h1[g][0];               // h1(s-1)
                #pragma unroll
                for (int q = 0; q < HS / 4; ++q) {
                    const float4 h4 = *(const float4*)(hp1 + 4 * q);
                    const float e[4] = {h4.x, h4.y, h4.z, h4.w};
                    #pragma unroll
                    for (int s = 0; s < 4; ++s) {
                        const int k = HS + 4 * q + s;
                        a0 = fmaf(e[s], w[0][k], a0);
                        a1 = fmaf(e[s], w[1][k], a1);
                        a2 = fmaf(e[s], w[2][k], a2);
                        a3 = fmaf(e[s], w[3][k], a3);
                    }
                }
                const float ii = sigmoid_fast(a0), ff = sigmoid_fast(a1);
                const float gg = tanh_fast(a2),    oo = sigmoid_fast(a3);
                cst = ff * cst + ii * gg;
                __builtin_amdgcn_wave_barrier();   // all h1(s-1) reads precede the write
                s_h1[g][u] = oo * tanh_fast(cst);
            }
        }
        __syncthreads();   // publishes s_h0[t&1]; protects WAR on s_h0[(t&1)] reuse
    }

    // ---- final FC on h1(T-1) ----
    if (wid == 1 && lane < BPB * HS && u == 0 && bg < NB_TOT) {
        float o = bfc[0];
        #pragma unroll
        for (int j = 0; j < HS; ++j) o = fmaf(s_h1[g][j], wfc[j], o);
        out[bg] = o;
    }
}

extern "C" void kernel_launch(void* const* d_in, const int* in_sizes, int n_in,
                              void* d_out, int out_size, void* d_ws, size_t ws_size,
                              hipStream_t stream) {
    const float* x    = (const float*)d_in[0];
    const float* wih0 = (const float*)d_in[1];
    const float* whh0 = (const float*)d_in[2];
    const float* bih0 = (const float*)d_in[3];
    const float* bhh0 = (const float*)d_in[4];
    const float* wih1 = (const float*)d_in[5];
    const float* whh1 = (const float*)d_in[6];
    const float* bih1 = (const float*)d_in[7];
    const float* bhh1 = (const float*)d_in[8];
    const float* wfc  = (const float*)d_in[9];
    const float* bfc  = (const float*)d_in[10];
    float* out = (float*)d_out;

    dim3 grid(NBLK), block(128);
    hipLaunchKernelGGL(lstm2_fc_kernel, grid, block, 0, stream,
                       x, wih0, whh0, bih0, bhh0,
                       wih1, whh1, bih1, bhh1, wfc, bfc, out);
}